// Round 6
// baseline (1071.685 us; speedup 1.0000x reference)
//
#include <hip/hip_runtime.h>
#include <math.h>

#define N_NODES 65536
#define BGRAPH  512

typedef float  f32x4 __attribute__((ext_vector_type(4)));
typedef short  s16x8 __attribute__((ext_vector_type(8)));

__device__ __forceinline__ float silu_f(float x){ return x / (1.0f + expf(-x)); }

__device__ __forceinline__ float f4c(const float4& v, int i){
  switch(i){ case 0: return v.x; case 1: return v.y; case 2: return v.z; default: return v.w; }
}

__device__ __forceinline__ unsigned short f2bf(float x){
  unsigned int u = __float_as_uint(x);
  return (unsigned short)((u + 0x7FFFu + ((u >> 16) & 1u)) >> 16);
}
__device__ __forceinline__ float bf2f(unsigned short h){
  return __uint_as_float(((unsigned int)h) << 16);
}
__device__ __forceinline__ void split2(float x, unsigned short& h, unsigned short& l){
  h = f2bf(x);
  l = f2bf(x - bf2f(h));
}

// acc += Ahi*Bhi + Ahi*Blo + Alo*Bhi   (split-bf16, ~1.5e-5 rel err vs fp32; lo*lo term dropped)
__device__ __forceinline__ f32x4 mfma3(s16x8 ah, s16x8 al, s16x8 bh, s16x8 bl, f32x4 c){
  c = __builtin_amdgcn_mfma_f32_16x16x32_bf16(ah, bh, c, 0, 0, 0);
  c = __builtin_amdgcn_mfma_f32_16x16x32_bf16(ah, bl, c, 0, 0, 0);
  c = __builtin_amdgcn_mfma_f32_16x16x32_bf16(al, bh, c, 0, 0, 0);
  return c;
}

// ---------------- init: zero graph accumulator ----------------
__global__ __launch_bounds__(256) void k_init(float* __restrict__ gmu){
  int t = threadIdx.x;
  #pragma unroll
  for (int j=0;j<6;j++) gmu[t + 256*j] = 0.0f;   // 1536 = B*3
}

// ---------------- prep: split weights to bf16 hi/lo, fragment-major ----------------
// frag layout: [K/32 windows][N/16 nsubs][64 lanes][8]:
//   elem(lane,j) = W[win*32 + 8*(lane>>4) + j][nsub*16 + (lane&15)]
// A and B share the same (lane,j)->k map, so any consistent k-permutation is exact
// (sum over k is permutation-invariant); only the C/D map is HW-layout-dependent (m89-verified).
__global__ __launch_bounds__(256) void k_prep(
    const float* __restrict__ g0w, const float* __restrict__ m1w, const float* __restrict__ m2w,
    unsigned short* __restrict__ g0h, unsigned short* __restrict__ g0l,
    unsigned short* __restrict__ m1h, unsigned short* __restrict__ m1l,
    unsigned short* __restrict__ m2h, unsigned short* __restrict__ m2l)
{
  int idx = blockIdx.x*256 + threadIdx.x;   // < 491520 = 1920*256 exactly
  const float* W; unsigned short *dh, *dl; int NS; int e;
  if (idx < 98304)      { e = idx;          W = g0w; dh = g0h; dl = g0l; NS = 24; }  // 256x384
  else if (idx < 360448){ e = idx - 98304;  W = m1w; dh = m1h; dl = m1l; NS = 32; }  // 512x512
  else                  { e = idx - 360448; W = m2w; dh = m2h; dl = m2l; NS = 16; }  // 512x256
  const int N = NS * 16;
  int win  = e / (NS * 512);
  int rem  = e % (NS * 512);
  int nsub = rem >> 9;
  int lane = (rem >> 3) & 63;
  int j    = e & 7;
  int k = win*32 + ((lane >> 4) << 3) + j;
  int n = (nsub << 4) + (lane & 15);
  float x = W[(size_t)k * N + n];
  unsigned short h, l; split2(x, h, l);
  dh[e] = h; dl[e] = l;
}

// ---------------- K1: wv = vector(196608,256) @ g0_w(256,384) via split-bf16 MFMA ----------------
// BM=192 rows (64 nodes, row = node*3+c), BN=64. grid=(bn=6, bm=1024): bn fast -> same A-tile
// temporally adjacent -> L3 absorbs the 6x A re-read. Fused epilogue: norm over c -> vvn0
// frag-major hi/lo (bn<4); cols>=256 -> vecw0 fp32 (bn in {4,5}).
__global__ __launch_bounds__(256) void k1_gate0(
    const float* __restrict__ vec,
    const unsigned short* __restrict__ g0h, const unsigned short* __restrict__ g0l,
    unsigned short* __restrict__ vnh, unsigned short* __restrict__ vnl,
    float* __restrict__ vecw0)
{
  // LDS: A_hi[12][64][8] @0 (12288B), A_lo @12288, B hi @24576 (4096B), B lo @28672;
  // epilogue reuses smem as fp32[192][65] (max byte 49916 < 49920)
  __shared__ __align__(16) char smem[49920];
  const int t  = threadIdx.x;
  const int l  = t & 63;
  const int wv = t >> 6;
  const int bn = blockIdx.x;          // 0..5
  const int bm = blockIdx.y;          // 0..1023
  const size_t m0 = (size_t)bm * 192;
  const int ni0 = bn * 4;

  f32x4 acc[3][4];
  #pragma unroll
  for (int a=0;a<3;a++)
    #pragma unroll
    for (int b=0;b<4;b++){ acc[a][b][0]=0.f; acc[a][b][1]=0.f; acc[a][b][2]=0.f; acc[a][b][3]=0.f; }

  for (int win = 0; win < 8; ++win){
    __syncthreads();
    // stage A inline-split: 3 units of 8 fp32 per thread
    #pragma unroll
    for (int uu=0; uu<3; ++uu){
      int u = t + 256*uu;
      int r = u >> 2;            // 0..191
      int o = u & 3;             // k-subgroup of 8
      const float* src = vec + (m0 + r)*256 + win*32 + o*8;
      float4 a0 = *(const float4*)src;
      float4 a1 = *(const float4*)(src + 4);
      float xv[8] = {a0.x,a0.y,a0.z,a0.w,a1.x,a1.y,a1.z,a1.w};
      s16x8 vh, vl;
      #pragma unroll
      for (int i=0;i<8;i++){ unsigned short h,lo; split2(xv[i],h,lo); vh[i]=(short)h; vl[i]=(short)lo; }
      int off = (((r >> 4) * 64) + (r & 15) + 16*o) * 16;
      *(s16x8*)(smem + off)         = vh;
      *(s16x8*)(smem + 12288 + off) = vl;
    }
    // stage B (pre-split frag-major): wave wv copies nsub ni0+wv, hi+lo
    {
      const unsigned short* sh = g0h + ((size_t)(win*24 + ni0 + wv))*512 + l*8;
      const unsigned short* sl = g0l + ((size_t)(win*24 + ni0 + wv))*512 + l*8;
      *(float4*)(smem + 24576 + (wv*64 + l)*16)        = *(const float4*)sh;
      *(float4*)(smem + 24576 + 4096 + (wv*64 + l)*16) = *(const float4*)sl;
    }
    __syncthreads();
    s16x8 ah[3], al[3], bh[4], bl[4];
    #pragma unroll
    for (int mi=0;mi<3;mi++){
      int off = ((3*wv + mi)*64 + l)*16;
      ah[mi] = *(const s16x8*)(smem + off);
      al[mi] = *(const s16x8*)(smem + 12288 + off);
    }
    #pragma unroll
    for (int ni=0;ni<4;ni++){
      int off = 24576 + (ni*64 + l)*16;
      bh[ni] = *(const s16x8*)(smem + off);
      bl[ni] = *(const s16x8*)(smem + 4096 + off);
    }
    #pragma unroll
    for (int mi=0;mi<3;mi++)
      #pragma unroll
      for (int ni=0;ni<4;ni++)
        acc[mi][ni] = mfma3(ah[mi], al[mi], bh[ni], bl[ni], acc[mi][ni]);
  }
  __syncthreads();
  // dump D to LDS fp32 [192][65] (padded stride). D map: col=lane&15, row=4*(lane>>4)+rg (m89).
  #pragma unroll
  for (int mi=0;mi<3;mi++)
    #pragma unroll
    for (int ni=0;ni<4;ni++)
      #pragma unroll
      for (int rg=0;rg<4;rg++){
        int row = 48*wv + 16*mi + 4*(l >> 4) + rg;
        int col = ni*16 + (l & 15);
        *(float*)(smem + (row*65 + col)*4) = acc[mi][ni][rg];
      }
  __syncthreads();
  if (bn < 4){
    #pragma unroll
    for (int i=0;i<16;i++){
      int idx = t + 256*i;
      int nl = idx >> 6, col = idx & 63;
      float x0 = *(const float*)(smem + ((3*nl+0)*65 + col)*4);
      float x1 = *(const float*)(smem + ((3*nl+1)*65 + col)*4);
      float x2 = *(const float*)(smem + ((3*nl+2)*65 + col)*4);
      float r = sqrtf(x0*x0 + x1*x1 + x2*x2);
      unsigned short h, lo; split2(r, h, lo);
      size_t gnode = (size_t)bm*64 + nl;
      int feat = bn*64 + col;
      size_t didx = ((size_t)(feat >> 5)*4096 + (gnode >> 4))*512
                  + ((gnode & 15) + 16*((feat & 31) >> 3))*8 + (feat & 7);
      vnh[didx] = h; vnl[didx] = lo;
    }
  } else {
    #pragma unroll
    for (int i=0;i<16;i++){
      int idx = t + 256*i;
      int nl = idx >> 6, col = idx & 63;
      int cw = bn*64 + col - 256;
      size_t gnode = (size_t)bm*64 + nl;
      #pragma unroll
      for (int c=0;c<3;c++)
        vecw0[(gnode*3 + c)*128 + cw] = *(const float*)(smem + ((3*nl+c)*65 + col)*4);
    }
  }
}

// ---------------- K2a: h = silu([scaler,vvn0](65536,512) @ m1w0(512,512) + b1), frag-major out ----------------
// grid=(bn=8, bm=512), bn fast for L3 locality on the A panel.
__global__ __launch_bounds__(256) void k2a_mlp0g1(
    const float* __restrict__ scaler,
    const unsigned short* __restrict__ vnh, const unsigned short* __restrict__ vnl,
    const unsigned short* __restrict__ m1h, const unsigned short* __restrict__ m1l,
    const float* __restrict__ m1b,
    unsigned short* __restrict__ hh, unsigned short* __restrict__ hl)
{
  // LDS: A_hi[8][64][8] @0 (8192), A_lo @8192, B hi @16384 (4096), B lo @20480
  __shared__ __align__(16) char smem[24576];
  const int t  = threadIdx.x;
  const int l  = t & 63;
  const int wv = t >> 6;
  const int bn = blockIdx.x;        // 0..7
  const int bm = blockIdx.y;        // 0..511 (128 nodes)
  const size_t m0 = (size_t)bm * 128;
  const int msub0 = bm * 8;
  const int ni0 = bn * 4;

  f32x4 acc[2][4];
  #pragma unroll
  for (int a=0;a<2;a++)
    #pragma unroll
    for (int b=0;b<4;b++){ acc[a][b][0]=0.f; acc[a][b][1]=0.f; acc[a][b][2]=0.f; acc[a][b][3]=0.f; }

  for (int kw = 0; kw < 16; ++kw){
    __syncthreads();
    if (kw < 8){
      // scaler fp32 inline split: 2 units of 8 fp32 (x cols 0..255)
      #pragma unroll
      for (int uu=0; uu<2; ++uu){
        int u = t + 256*uu;
        int r = u >> 2;          // 0..127
        int o = u & 3;
        const float* src = scaler + (m0 + r)*256 + kw*32 + o*8;
        float4 a0 = *(const float4*)src;
        float4 a1 = *(const float4*)(src + 4);
        float xv[8] = {a0.x,a0.y,a0.z,a0.w,a1.x,a1.y,a1.z,a1.w};
        s16x8 vh, vl;
        #pragma unroll
        for (int i=0;i<8;i++){ unsigned short h,lo; split2(xv[i],h,lo); vh[i]=(short)h; vl[i]=(short)lo; }
        int off = (((r >> 4)*64) + (r & 15) + 16*o)*16;
        *(s16x8*)(smem + off)        = vh;
        *(s16x8*)(smem + 8192 + off) = vl;
      }
    } else {
      // vvn0 frag-major linear copy (x cols 256..511)
      int v = kw - 8;
      #pragma unroll
      for (int half=0; half<2; ++half){
        int sub = wv + 4*half;
        size_t so = ((size_t)(v*4096 + msub0 + sub))*512 + l*8;
        *(float4*)(smem + sub*1024 + l*16)        = *(const float4*)(vnh + so);
        *(float4*)(smem + 8192 + sub*1024 + l*16) = *(const float4*)(vnl + so);
      }
    }
    { // B copy: wave wv -> nsub ni0+wv
      size_t so = ((size_t)(kw*32 + ni0 + wv))*512 + l*8;
      *(float4*)(smem + 16384 + (wv*64 + l)*16)        = *(const float4*)(m1h + so);
      *(float4*)(smem + 16384 + 4096 + (wv*64 + l)*16) = *(const float4*)(m1l + so);
    }
    __syncthreads();
    s16x8 ah[2], al[2], bh[4], bl[4];
    #pragma unroll
    for (int mi=0;mi<2;mi++){
      int off = ((2*wv + mi)*64 + l)*16;
      ah[mi] = *(const s16x8*)(smem + off);
      al[mi] = *(const s16x8*)(smem + 8192 + off);
    }
    #pragma unroll
    for (int ni=0;ni<4;ni++){
      int off = 16384 + (ni*64 + l)*16;
      bh[ni] = *(const s16x8*)(smem + off);
      bl[ni] = *(const s16x8*)(smem + 4096 + off);
    }
    #pragma unroll
    for (int mi=0;mi<2;mi++)
      #pragma unroll
      for (int ni=0;ni<4;ni++)
        acc[mi][ni] = mfma3(ah[mi], al[mi], bh[ni], bl[ni], acc[mi][ni]);
  }
  // epilogue: bias + silu + split -> h frag-major
  #pragma unroll
  for (int mi=0;mi<2;mi++)
    #pragma unroll
    for (int ni=0;ni<4;ni++){
      int col = bn*64 + ni*16 + (l & 15);
      float bias = m1b[col];
      #pragma unroll
      for (int rg=0;rg<4;rg++){
        size_t node = m0 + 32*wv + 16*mi + 4*(l >> 4) + rg;
        float y = silu_f(acc[mi][ni][rg] + bias);
        unsigned short h, lo; split2(y, h, lo);
        size_t didx = ((size_t)(col >> 5)*4096 + (node >> 4))*512
                    + ((node & 15) + 16*((col & 31) >> 3))*8 + (col & 7);
        hh[didx] = h; hl[didx] = lo;
      }
    }
}

// ---------------- K2b: y = h(65536,512) @ m2w0(512,256) + b2 -> q0=silu(y[:,:128]), gate0=y[:,128:] ----------------
// grid=(bn=4, bm=512), bn fast.
__global__ __launch_bounds__(256) void k2b_mlp0g2(
    const unsigned short* __restrict__ hh, const unsigned short* __restrict__ hl,
    const unsigned short* __restrict__ m2h, const unsigned short* __restrict__ m2l,
    const float* __restrict__ m2b,
    float* __restrict__ q0, float* __restrict__ gate0)
{
  __shared__ __align__(16) char smem[24576];
  const int t  = threadIdx.x;
  const int l  = t & 63;
  const int wv = t >> 6;
  const int bn = blockIdx.x;        // 0..3
  const int bm = blockIdx.y;        // 0..511
  const size_t m0 = (size_t)bm * 128;
  const int msub0 = bm * 8;
  const int ni0 = bn * 4;

  f32x4 acc[2][4];
  #pragma unroll
  for (int a=0;a<2;a++)
    #pragma unroll
    for (int b=0;b<4;b++){ acc[a][b][0]=0.f; acc[a][b][1]=0.f; acc[a][b][2]=0.f; acc[a][b][3]=0.f; }

  for (int kw = 0; kw < 16; ++kw){
    __syncthreads();
    #pragma unroll
    for (int half=0; half<2; ++half){
      int sub = wv + 4*half;
      size_t so = ((size_t)(kw*4096 + msub0 + sub))*512 + l*8;
      *(float4*)(smem + sub*1024 + l*16)        = *(const float4*)(hh + so);
      *(float4*)(smem + 8192 + sub*1024 + l*16) = *(const float4*)(hl + so);
    }
    {
      size_t so = ((size_t)(kw*16 + ni0 + wv))*512 + l*8;
      *(float4*)(smem + 16384 + (wv*64 + l)*16)        = *(const float4*)(m2h + so);
      *(float4*)(smem + 16384 + 4096 + (wv*64 + l)*16) = *(const float4*)(m2l + so);
    }
    __syncthreads();
    s16x8 ah[2], al[2], bh[4], bl[4];
    #pragma unroll
    for (int mi=0;mi<2;mi++){
      int off = ((2*wv + mi)*64 + l)*16;
      ah[mi] = *(const s16x8*)(smem + off);
      al[mi] = *(const s16x8*)(smem + 8192 + off);
    }
    #pragma unroll
    for (int ni=0;ni<4;ni++){
      int off = 16384 + (ni*64 + l)*16;
      bh[ni] = *(const s16x8*)(smem + off);
      bl[ni] = *(const s16x8*)(smem + 4096 + off);
    }
    #pragma unroll
    for (int mi=0;mi<2;mi++)
      #pragma unroll
      for (int ni=0;ni<4;ni++)
        acc[mi][ni] = mfma3(ah[mi], al[mi], bh[ni], bl[ni], acc[mi][ni]);
  }
  // epilogue
  #pragma unroll
  for (int mi=0;mi<2;mi++)
    #pragma unroll
    for (int ni=0;ni<4;ni++){
      int col = bn*64 + ni*16 + (l & 15);     // 0..255
      float bias = m2b[col];
      #pragma unroll
      for (int rg=0;rg<4;rg++){
        size_t node = m0 + 32*wv + 16*mi + 4*(l >> 4) + rg;
        float y = acc[mi][ni][rg] + bias;
        if (col < 128) q0[node*128 + col] = silu_f(y);
        else           gate0[node*128 + col - 128] = y;
      }
    }
}

// ---------------- K3: mu = gate0*vecw0; wv1 = mu(48,128) @ g1_w(128,129); fused norm (fp32 VALU) ----------------
__global__ __launch_bounds__(256) void k3_gate1(
    const float* __restrict__ gate0, const float* __restrict__ vecw0,
    const float* __restrict__ g1w,
    float* __restrict__ vvn1, float* __restrict__ vecw1)
{
  __shared__ float gs[16*128];
  __shared__ float ms[48*132];
  __shared__ float Bs[16*132];
  __shared__ float wcol[128];
  const int t = threadIdx.x;
  const int node0 = blockIdx.x * 16;

  {
    const float4* G4 = (const float4*)(gate0 + (size_t)node0*128);
    float4* gs4 = (float4*)gs;
    #pragma unroll
    for (int j=0;j<2;j++) gs4[t + 256*j] = G4[t + 256*j];
    if (t < 128) wcol[t] = g1w[t*129 + 128];
  }
  __syncthreads();
  {
    const float4* V4 = (const float4*)(vecw0 + (size_t)node0*384);
    #pragma unroll
    for (int j=0;j<6;j++){
      int i4 = t + 256*j;
      int ln = i4 / 96; int rem4 = i4 - ln*96;
      int c = rem4 >> 5; int i = (rem4 & 31) * 4;
      float4 v = V4[i4];
      int row = ln*3 + c;
      ms[row*132 + i + 0] = v.x * gs[ln*128 + i + 0];
      ms[row*132 + i + 1] = v.y * gs[ln*128 + i + 1];
      ms[row*132 + i + 2] = v.z * gs[ln*128 + i + 2];
      ms[row*132 + i + 3] = v.w * gs[ln*128 + i + 3];
    }
  }

  const int tc = t & 63;
  const int tr = t >> 6;
  float acc0[12], acc1[12];
  #pragma unroll
  for (int j=0;j<12;j++){ acc0[j]=0.0f; acc1[j]=0.0f; }

  for (int k0=0;k0<128;k0+=16){
    __syncthreads();
    #pragma unroll
    for (int j=0;j<9;j++){
      int idx = t + 256*j;
      if (idx < 2064){
        int row = idx / 129; int col = idx - row*129;
        Bs[row*132 + col] = g1w[(size_t)k0*129 + idx];
      }
    }
    __syncthreads();
    #pragma unroll
    for (int kg=0;kg<4;kg++){
      float4 av[12];
      #pragma unroll
      for (int j=0;j<12;j++) av[j] = *(const float4*)&ms[(tr*12+j)*132 + k0 + kg*4];
      #pragma unroll
      for (int kk=0;kk<4;kk++){
        float b0 = Bs[(kg*4+kk)*132 + tc];
        float b1 = Bs[(kg*4+kk)*132 + tc + 64];
        #pragma unroll
        for (int j=0;j<12;j++){
          float a = f4c(av[j], kk);
          acc0[j] = fmaf(a, b0, acc0[j]);
          acc1[j] = fmaf(a, b1, acc1[j]);
        }
      }
    }
  }
  #pragma unroll
  for (int ln=0; ln<4; ln++){
    const int node = node0 + tr*4 + ln;
    float x0=acc0[ln*3+0], x1=acc0[ln*3+1], x2=acc0[ln*3+2];
    vvn1[(size_t)node*128 + tc] = sqrtf(x0*x0+x1*x1+x2*x2);
    float y0=acc1[ln*3+0], y1=acc1[ln*3+1], y2=acc1[ln*3+2];
    vvn1[(size_t)node*128 + tc + 64] = sqrtf(y0*y0+y1*y1+y2*y2);
  }
  __syncthreads();
  if (t < 48){
    float s = 0.0f;
    #pragma unroll
    for (int k=0;k<128;k+=4){
      float4 a = *(const float4*)&ms[t*132 + k];
      s = fmaf(a.x, wcol[k+0], s);
      s = fmaf(a.y, wcol[k+1], s);
      s = fmaf(a.z, wcol[k+2], s);
      s = fmaf(a.w, wcol[k+3], s);
    }
    vecw1[((size_t)node0 + t/3)*3 + (t%3)] = s;
  }
}

// ---------------- K4: MLP1 + node_mu + run-length-compressed segment-sum ----------------
__global__ __launch_bounds__(256) void k4_mlp1(
    const float* __restrict__ q0, const float* __restrict__ vvn1,
    const float* __restrict__ m1w, const float* __restrict__ m1b,
    const float* __restrict__ m2w, const float* __restrict__ m2b,
    const float* __restrict__ vecw1,
    const float* __restrict__ pos, const float* __restrict__ mc,
    const int* __restrict__ bidx, float* __restrict__ gmu)
{
  __shared__ float xs[16*256];
  __shared__ float Bs[8*256];
  __shared__ float snm[16][3];
  __shared__ int   sbi[16];
  const int t = threadIdx.x;
  const int node0 = blockIdx.x * 16;

  {
    const float4* Q4 = (const float4*)(q0   + (size_t)node0*128);
    const float4* N4 = (const float4*)(vvn1 + (size_t)node0*128);
    #pragma unroll
    for (int j=0;j<2;j++){
      int i4 = t + 256*j; int r = i4 >> 5; int c4 = i4 & 31;
      *(float4*)&xs[r*256 + c4*4]       = Q4[i4];
      *(float4*)&xs[r*256 + 128 + c4*4] = N4[i4];
    }
  }

  const int tr = t >> 6;
  const int c0 = (t & 63) * 4;
  float4 acc[4];
  #pragma unroll
  for (int j=0;j<4;j++) acc[j] = make_float4(0.f,0.f,0.f,0.f);

  for (int k0=0;k0<256;k0+=8){
    __syncthreads();
    const float4* W4 = (const float4*)(m1w + (size_t)k0*256);
    float4* Bs4 = (float4*)Bs;
    #pragma unroll
    for (int j=0;j<2;j++) Bs4[t + 256*j] = W4[t + 256*j];
    __syncthreads();
    #pragma unroll
    for (int kg=0;kg<2;kg++){
      float4 av[4];
      #pragma unroll
      for (int j=0;j<4;j++) av[j] = *(const float4*)&xs[(tr*4+j)*256 + k0 + kg*4];
      #pragma unroll
      for (int kk=0;kk<4;kk++){
        float4 b4 = *(const float4*)&Bs[(kg*4+kk)*256 + c0];
        #pragma unroll
        for (int j=0;j<4;j++){
          float a = f4c(av[j], kk);
          acc[j].x = fmaf(a, b4.x, acc[j].x);
          acc[j].y = fmaf(a, b4.y, acc[j].y);
          acc[j].z = fmaf(a, b4.z, acc[j].z);
          acc[j].w = fmaf(a, b4.w, acc[j].w);
        }
      }
    }
  }
  __syncthreads();
  {
    const float4 b1 = *(const float4*)&m1b[c0];
    #pragma unroll
    for (int j=0;j<4;j++){
      float4 y;
      y.x = silu_f(acc[j].x + b1.x);
      y.y = silu_f(acc[j].y + b1.y);
      y.z = silu_f(acc[j].z + b1.z);
      y.w = silu_f(acc[j].w + b1.w);
      *(float4*)&xs[(tr*4+j)*256 + c0] = y;
    }
  }
  __syncthreads();

  const int ln = t >> 4;
  const int ks = t & 15;
  float p0 = 0.0f, p1 = 0.0f;
  #pragma unroll
  for (int kk=0;kk<4;kk++){
    float4 h4 = *(const float4*)&xs[ln*256 + ks*16 + kk*4];
    #pragma unroll
    for (int e=0;e<4;e++){
      int k = ks*16 + kk*4 + e;
      float h = f4c(h4, e);
      p0 = fmaf(h, m2w[k*2 + 0], p0);
      p1 = fmaf(h, m2w[k*2 + 1], p1);
    }
  }
  #pragma unroll
  for (int o=8;o>0;o>>=1){
    p0 += __shfl_down(p0, o, 16);
    p1 += __shfl_down(p1, o, 16);
  }
  if (ks == 0){
    const int node = node0 + ln;
    const float q2 = p0 + m2b[0];    // NOTE: no silu on second-gate q (matches reference)
    const float g2 = p1 + m2b[1];
    const int bi = bidx[node];
    sbi[ln] = bi;
    #pragma unroll
    for (int c=0;c<3;c++){
      float mcv = pos[(size_t)node*3 + c] - mc[(size_t)bi*3 + c];
      snm[ln][c] = fmaf(q2, mcv, g2 * vecw1[(size_t)node*3 + c]);
    }
  }
  __syncthreads();
  if (t < 3){
    const int c = t;
    float run = snm[0][c];
    int bi = sbi[0];
    #pragma unroll
    for (int i=1;i<16;i++){
      if (sbi[i] != bi){
        atomicAdd(&gmu[bi*3 + c], run);
        bi = sbi[i]; run = 0.0f;
      }
      run += snm[i][c];
    }
    atomicAdd(&gmu[bi*3 + c], run);
  }
}

// ---------------- K5: out = ||graph_mu|| ----------------
__global__ __launch_bounds__(256) void k5_norm(const float* __restrict__ gmu, float* __restrict__ out){
  int b = blockIdx.x*256 + threadIdx.x;
  if (b < BGRAPH){
    float x = gmu[b*3+0], y = gmu[b*3+1], z = gmu[b*3+2];
    out[b] = sqrtf(x*x + y*y + z*z);
  }
}

extern "C" void kernel_launch(void* const* d_in, const int* in_sizes, int n_in,
                              void* d_out, int out_size, void* d_ws, size_t ws_size,
                              hipStream_t stream) {
  const float* pos    = (const float*)d_in[0];
  const float* mc     = (const float*)d_in[1];
  const float* scaler = (const float*)d_in[2];
  const float* vec    = (const float*)d_in[3];
  const int*   bidx   = (const int*)d_in[4];
  const float* g0w    = (const float*)d_in[6];
  const float* m1w0   = (const float*)d_in[7];
  const float* m1b0   = (const float*)d_in[8];
  const float* m2w0   = (const float*)d_in[9];
  const float* m2b0   = (const float*)d_in[10];
  const float* g1w    = (const float*)d_in[11];
  const float* m1w1   = (const float*)d_in[12];
  const float* m1b1   = (const float*)d_in[13];
  const float* m2w1   = (const float*)d_in[14];
  const float* m2b1   = (const float*)d_in[15];

  // Workspace layout with lifetime aliasing. Total = 303,962,112 B (~290 MiB).
  //  [0, 6144)                      gmu (1536 f)
  //  [6144, 1972224)                weight splits (g0/m1/m2 hi+lo)
  //  [1972224, 102635520)           vecw0 fp32 (live K1 -> K3)
  //  [102635520, 169744384) regB:   vnh/vnl (K1 -> K2a), THEN q0+gate0 (K2b -> K3/K4)
  //  [169744384, 303962112) regC:   hh/hl (K2a -> K2b), THEN vvn1+vecw1 (K3 -> K4)
  char* W = (char*)d_ws;
  float* gmu = (float*)W;
  unsigned short* g0h = (unsigned short*)(W + 6144);
  unsigned short* g0l = (unsigned short*)(W + 202752);
  unsigned short* m1h = (unsigned short*)(W + 399360);
  unsigned short* m1l = (unsigned short*)(W + 923648);
  unsigned short* m2h = (unsigned short*)(W + 1447936);
  unsigned short* m2l = (unsigned short*)(W + 1710080);
  float* vecw0 = (float*)(W + 1972224);
  char* regB = W + 102635520;
  unsigned short* vnh = (unsigned short*)regB;
  unsigned short* vnl = vnh + 16777216;
  float* q0    = (float*)regB;           // aliases vnh/vnl after K2a
  float* gate0 = q0 + 8388608;
  char* regC = W + 169744384;
  unsigned short* hh = (unsigned short*)regC;
  unsigned short* hl = hh + 33554432;
  float* vvn1  = (float*)regC;           // aliases hh/hl after K2b
  float* vecw1 = vvn1 + 8388608;

  float* out = (float*)d_out;

  hipLaunchKernelGGL(k_init, dim3(1), dim3(256), 0, stream, gmu);
  hipLaunchKernelGGL(k_prep, dim3(1920), dim3(256), 0, stream,
                     g0w, m1w0, m2w0, g0h, g0l, m1h, m1l, m2h, m2l);
  hipLaunchKernelGGL(k1_gate0, dim3(6, 1024), dim3(256), 0, stream,
                     vec, g0h, g0l, vnh, vnl, vecw0);
  hipLaunchKernelGGL(k2a_mlp0g1, dim3(8, 512), dim3(256), 0, stream,
                     scaler, vnh, vnl, m1h, m1l, m1b0, hh, hl);
  hipLaunchKernelGGL(k2b_mlp0g2, dim3(4, 512), dim3(256), 0, stream,
                     hh, hl, m2h, m2l, m2b0, q0, gate0);
  hipLaunchKernelGGL(k3_gate1, dim3(N_NODES/16), dim3(256), 0, stream,
                     gate0, vecw0, g1w, vvn1, vecw1);
  hipLaunchKernelGGL(k4_mlp1, dim3(N_NODES/16), dim3(256), 0, stream,
                     q0, vvn1, m1w1, m1b1, m2w1, m2b1, vecw1, pos, mc, bidx, gmu);
  hipLaunchKernelGGL(k5_norm, dim3(2), dim3(256), 0, stream, gmu, out);
}